// Round 18
// baseline (178.939 us; speedup 1.0000x reference)
//
#include <hip/hip_runtime.h>
#include <stdint.h>

// Quant3Linear GEMV: y = x @ (scales.T * unpack3(qweight) - zeros.T) + bias
//   x: (1, 8192) f32 | qweight: (768, 28672) i32 | scales,zeros: (28672,1) | bias: (28672,)
// Decomposition: y[o] = scales[o]*dot(x, q[:,o]) - zeros[o]*sum(x) + bias[o]
//
// R18: MEASUREMENT ROUND 4 -- R16's best kernel (138.7us: inline-asm 3-VALU/
// elem dot + depth-2 counted-vmcnt sliding window), body byte-identical,
// amplified 3x via blockIdx.z (z<2 -> dummy atomics in d_ws, z==2 -> real
// out). Purpose: the asm kernel has NEVER been profiled (all VALUBusy data
// is from the pre-asm code); a ~78us dispatch clears the ~52us fill cutoff.
// Readout (pre-committed):
//   VALUBusy>=70% -> asm kernel genuinely issue-bound at its real emitted
//       count -> force paired ops or declare ceiling;
//   VALUBusy 35-55% -> stall-dominated (latency covered per R17) -> FETCH/
//       Occupancy discriminate BW vs co-residency;
//   per-layer (dur-138.7)/2 <= 18us -> residual is launch overhead ->
//       138.7 is the floor, ROOFLINE.
// History: depth-2 prefetch -3.9us (R16); depth-4 neutral (R17, window
//   saturated); asm 3.3/elem == HIP 7.4/elem (R15, not inst-count-bound
//   pre-pipeline); TLP dead (R1,R11); memory dead (R10 hot==cold); fences
//   toxic (R8); coop fails (R7).

constexpr int O_FEAT  = 28672;
constexpr int IN_FEAT = 8192;
constexpr int NGROUP  = IN_FEAT / 32;   // 256 groups (3 packed int32 rows each)
constexpr int SPLIT   = 32;             // split-K factor
constexpr int GPB     = NGROUP / SPLIT; // 8 groups per thread
constexpr int O4      = O_FEAT / 4;     // uint4 columns per packed row
constexpr int NBX     = O4 / 64;        // 112 column groups (256 cols each)
constexpr int PFD     = 2;              // prefetch depth (R16 best; R17 d4 neutral)
constexpr int NREP    = 3;              // amplification layers (z)

// One regular element (field at bit SH of per-column word) for 4 columns.
template <int SH>
__device__ __forceinline__ void q3e4(uint32_t va, uint32_t vb, uint32_t vc, uint32_t vd,
                                     uint32_t m7, float xj,
                                     float& A, float& B, float& C, float& D) {
  float t0, t1, t2, t3;
  if constexpr (SH < 20) {
    asm("v_lshlrev_b32 %0, %12, %8\n\t"
        "v_lshlrev_b32 %1, %12, %9\n\t"
        "v_lshlrev_b32 %2, %12, %10\n\t"
        "v_lshlrev_b32 %3, %12, %11\n\t"
        "v_and_or_b32 %0, %0, %13, 2.0\n\t"
        "v_and_or_b32 %1, %1, %13, 2.0\n\t"
        "v_and_or_b32 %2, %2, %13, 2.0\n\t"
        "v_and_or_b32 %3, %3, %13, 2.0\n\t"
        "v_fmac_f32 %4, %14, %0\n\t"
        "v_fmac_f32 %5, %14, %1\n\t"
        "v_fmac_f32 %6, %14, %2\n\t"
        "v_fmac_f32 %7, %14, %3"
        : "=&v"(t0), "=&v"(t1), "=&v"(t2), "=&v"(t3),
          "+v"(A), "+v"(B), "+v"(C), "+v"(D)
        : "v"(va), "v"(vb), "v"(vc), "v"(vd), "n"(20 - SH), "s"(m7), "v"(xj));
  } else if constexpr (SH == 20) {
    asm("v_and_or_b32 %0, %8, %12, 2.0\n\t"
        "v_and_or_b32 %1, %9, %12, 2.0\n\t"
        "v_and_or_b32 %2, %10, %12, 2.0\n\t"
        "v_and_or_b32 %3, %11, %12, 2.0\n\t"
        "v_fmac_f32 %4, %13, %0\n\t"
        "v_fmac_f32 %5, %13, %1\n\t"
        "v_fmac_f32 %6, %13, %2\n\t"
        "v_fmac_f32 %7, %13, %3"
        : "=&v"(t0), "=&v"(t1), "=&v"(t2), "=&v"(t3),
          "+v"(A), "+v"(B), "+v"(C), "+v"(D)
        : "v"(va), "v"(vb), "v"(vc), "v"(vd), "s"(m7), "v"(xj));
  } else {
    asm("v_lshrrev_b32 %0, %12, %8\n\t"
        "v_lshrrev_b32 %1, %12, %9\n\t"
        "v_lshrrev_b32 %2, %12, %10\n\t"
        "v_lshrrev_b32 %3, %12, %11\n\t"
        "v_and_or_b32 %0, %0, %13, 2.0\n\t"
        "v_and_or_b32 %1, %1, %13, 2.0\n\t"
        "v_and_or_b32 %2, %2, %13, 2.0\n\t"
        "v_and_or_b32 %3, %3, %13, 2.0\n\t"
        "v_fmac_f32 %4, %14, %0\n\t"
        "v_fmac_f32 %5, %14, %1\n\t"
        "v_fmac_f32 %6, %14, %2\n\t"
        "v_fmac_f32 %7, %14, %3"
        : "=&v"(t0), "=&v"(t1), "=&v"(t2), "=&v"(t3),
          "+v"(A), "+v"(B), "+v"(C), "+v"(D)
        : "v"(va), "v"(vb), "v"(vc), "v"(vd), "n"(SH - 20), "s"(m7), "v"(xj));
  }
}

// e10 = (w0>>30)|((w1&1)<<2): u = ((w0>>10)&0x300000)|((w1<<22)&0x400000)|2.0
__device__ __forceinline__ void q3e4_s10(uint4 wa, uint4 wb, uint32_t m3, uint32_t m4,
                                         float xj, float& A, float& B, float& C, float& D) {
  float t0, t1, t2, t3, u0, u1, u2, u3;
  asm("v_lshrrev_b32 %0, 10, %12\n\t"
      "v_lshrrev_b32 %1, 10, %13\n\t"
      "v_lshrrev_b32 %2, 10, %14\n\t"
      "v_lshrrev_b32 %3, 10, %15\n\t"
      "v_lshlrev_b32 %4, 22, %16\n\t"
      "v_lshlrev_b32 %5, 22, %17\n\t"
      "v_lshlrev_b32 %6, 22, %18\n\t"
      "v_lshlrev_b32 %7, 22, %19\n\t"
      "v_and_or_b32 %0, %0, %20, 2.0\n\t"
      "v_and_or_b32 %1, %1, %20, 2.0\n\t"
      "v_and_or_b32 %2, %2, %20, 2.0\n\t"
      "v_and_or_b32 %3, %3, %20, 2.0\n\t"
      "v_and_or_b32 %0, %4, %21, %0\n\t"
      "v_and_or_b32 %1, %5, %21, %1\n\t"
      "v_and_or_b32 %2, %6, %21, %2\n\t"
      "v_and_or_b32 %3, %7, %21, %3\n\t"
      "v_fmac_f32 %8, %22, %0\n\t"
      "v_fmac_f32 %9, %22, %1\n\t"
      "v_fmac_f32 %10, %22, %2\n\t"
      "v_fmac_f32 %11, %22, %3"
      : "=&v"(t0), "=&v"(t1), "=&v"(t2), "=&v"(t3),
        "=&v"(u0), "=&v"(u1), "=&v"(u2), "=&v"(u3),
        "+v"(A), "+v"(B), "+v"(C), "+v"(D)
      : "v"(wa.x), "v"(wa.y), "v"(wa.z), "v"(wa.w),
        "v"(wb.x), "v"(wb.y), "v"(wb.z), "v"(wb.w),
        "s"(m3), "s"(m4), "v"(xj));
}

// e21 = (w1>>31)|((w2&3)<<1): u = ((w1>>11)&0x100000)|((w2<<21)&0x600000)|2.0
__device__ __forceinline__ void q3e4_s21(uint4 wb, uint4 wc, uint32_t m1, uint32_t m6,
                                         float xj, float& A, float& B, float& C, float& D) {
  float t0, t1, t2, t3, u0, u1, u2, u3;
  asm("v_lshrrev_b32 %0, 11, %12\n\t"
      "v_lshrrev_b32 %1, 11, %13\n\t"
      "v_lshrrev_b32 %2, 11, %14\n\t"
      "v_lshrrev_b32 %3, 11, %15\n\t"
      "v_lshlrev_b32 %4, 21, %16\n\t"
      "v_lshlrev_b32 %5, 21, %17\n\t"
      "v_lshlrev_b32 %6, 21, %18\n\t"
      "v_lshlrev_b32 %7, 21, %19\n\t"
      "v_and_or_b32 %0, %0, %20, 2.0\n\t"
      "v_and_or_b32 %1, %1, %20, 2.0\n\t"
      "v_and_or_b32 %2, %2, %20, 2.0\n\t"
      "v_and_or_b32 %3, %3, %20, 2.0\n\t"
      "v_and_or_b32 %0, %4, %21, %0\n\t"
      "v_and_or_b32 %1, %5, %21, %1\n\t"
      "v_and_or_b32 %2, %6, %21, %2\n\t"
      "v_and_or_b32 %3, %7, %21, %3\n\t"
      "v_fmac_f32 %8, %22, %0\n\t"
      "v_fmac_f32 %9, %22, %1\n\t"
      "v_fmac_f32 %10, %22, %2\n\t"
      "v_fmac_f32 %11, %22, %3"
      : "=&v"(t0), "=&v"(t1), "=&v"(t2), "=&v"(t3),
        "=&v"(u0), "=&v"(u1), "=&v"(u2), "=&v"(u3),
        "+v"(A), "+v"(B), "+v"(C), "+v"(D)
      : "v"(wb.x), "v"(wb.y), "v"(wb.z), "v"(wb.w),
        "v"(wc.x), "v"(wc.y), "v"(wc.z), "v"(wc.w),
        "s"(m1), "s"(m6), "v"(xj));
}

__global__ __launch_bounds__(64) void q3_onepass(const float* __restrict__ x,
                                                 const uint4* __restrict__ qw4,
                                                 const float* __restrict__ scales,
                                                 const float* __restrict__ zeros,
                                                 const float* __restrict__ bias,
                                                 float* __restrict__ out,
                                                 float* __restrict__ dummy) {
  const int tcol4 = blockIdx.x * 64 + threadIdx.x;   // index in units of 4 columns
  const int g0    = blockIdx.y * GPB;
  const uint4* qp = qw4 + (size_t)(3 * g0) * O4 + tcol4;

  // Stage this block's x chunk (256 floats = 1 KB, raw) in LDS.
  __shared__ float xs[GPB * 32];
  const float4 xt = reinterpret_cast<const float4*>(x + g0 * 32)[threadIdx.x];
  reinterpret_cast<float4*>(xs)[threadIdx.x] = xt;

  const uint32_t m7 = 0x00700000u, m3 = 0x00300000u, m4 = 0x00400000u,
                 m1 = 0x00100000u, m6 = 0x00600000u;

  float A = 0.f, B = 0.f, C = 0.f, D = 0.f;   // 4 column accumulators

  // Depth-2 sliding window (R16 best): w[g] filled 2 iterations ahead.
  // Issue order == consumption order -> counted vmcnt, never 0 mid-loop.
  uint4 w[GPB][3];
  #pragma unroll
  for (int g = 0; g < PFD; ++g) {
    w[g][0] = qp[0]; w[g][1] = qp[O4]; w[g][2] = qp[2 * O4];
    qp += 3 * O4;
  }

  #pragma unroll
  for (int g = 0; g < GPB; ++g) {
    if (g + PFD < GPB) {   // compile-time after unroll
      w[g + PFD][0] = qp[0]; w[g + PFD][1] = qp[O4]; w[g + PFD][2] = qp[2 * O4];
      qp += 3 * O4;
    }
    const uint4 wa = w[g][0], wb = w[g][1], wc = w[g][2];

    float xv[32];
    const float4* s4 = reinterpret_cast<const float4*>(&xs[g * 32]);
    #pragma unroll
    for (int u = 0; u < 8; ++u) {
      float4 t = s4[u];
      xv[4 * u + 0] = t.x; xv[4 * u + 1] = t.y;
      xv[4 * u + 2] = t.z; xv[4 * u + 3] = t.w;
    }

    // word0: e0..e9 at sh=3j
    q3e4<0>(wa.x, wa.y, wa.z, wa.w, m7, xv[0], A, B, C, D);
    q3e4<3>(wa.x, wa.y, wa.z, wa.w, m7, xv[1], A, B, C, D);
    q3e4<6>(wa.x, wa.y, wa.z, wa.w, m7, xv[2], A, B, C, D);
    q3e4<9>(wa.x, wa.y, wa.z, wa.w, m7, xv[3], A, B, C, D);
    q3e4<12>(wa.x, wa.y, wa.z, wa.w, m7, xv[4], A, B, C, D);
    q3e4<15>(wa.x, wa.y, wa.z, wa.w, m7, xv[5], A, B, C, D);
    q3e4<18>(wa.x, wa.y, wa.z, wa.w, m7, xv[6], A, B, C, D);
    q3e4<21>(wa.x, wa.y, wa.z, wa.w, m7, xv[7], A, B, C, D);
    q3e4<24>(wa.x, wa.y, wa.z, wa.w, m7, xv[8], A, B, C, D);
    q3e4<27>(wa.x, wa.y, wa.z, wa.w, m7, xv[9], A, B, C, D);
    // e10 split w0/w1
    q3e4_s10(wa, wb, m3, m4, xv[10], A, B, C, D);
    // word1: e11..e20 at sh=3j+1
    q3e4<1>(wb.x, wb.y, wb.z, wb.w, m7, xv[11], A, B, C, D);
    q3e4<4>(wb.x, wb.y, wb.z, wb.w, m7, xv[12], A, B, C, D);
    q3e4<7>(wb.x, wb.y, wb.z, wb.w, m7, xv[13], A, B, C, D);
    q3e4<10>(wb.x, wb.y, wb.z, wb.w, m7, xv[14], A, B, C, D);
    q3e4<13>(wb.x, wb.y, wb.z, wb.w, m7, xv[15], A, B, C, D);
    q3e4<16>(wb.x, wb.y, wb.z, wb.w, m7, xv[16], A, B, C, D);
    q3e4<19>(wb.x, wb.y, wb.z, wb.w, m7, xv[17], A, B, C, D);
    q3e4<22>(wb.x, wb.y, wb.z, wb.w, m7, xv[18], A, B, C, D);
    q3e4<25>(wb.x, wb.y, wb.z, wb.w, m7, xv[19], A, B, C, D);
    q3e4<28>(wb.x, wb.y, wb.z, wb.w, m7, xv[20], A, B, C, D);
    // e21 split w1/w2
    q3e4_s21(wb, wc, m1, m6, xv[21], A, B, C, D);
    // word2: e22..e31 at sh=3j+2
    q3e4<2>(wc.x, wc.y, wc.z, wc.w, m7, xv[22], A, B, C, D);
    q3e4<5>(wc.x, wc.y, wc.z, wc.w, m7, xv[23], A, B, C, D);
    q3e4<8>(wc.x, wc.y, wc.z, wc.w, m7, xv[24], A, B, C, D);
    q3e4<11>(wc.x, wc.y, wc.z, wc.w, m7, xv[25], A, B, C, D);
    q3e4<14>(wc.x, wc.y, wc.z, wc.w, m7, xv[26], A, B, C, D);
    q3e4<17>(wc.x, wc.y, wc.z, wc.w, m7, xv[27], A, B, C, D);
    q3e4<20>(wc.x, wc.y, wc.z, wc.w, m7, xv[28], A, B, C, D);
    q3e4<23>(wc.x, wc.y, wc.z, wc.w, m7, xv[29], A, B, C, D);
    q3e4<26>(wc.x, wc.y, wc.z, wc.w, m7, xv[30], A, B, C, D);
    q3e4<29>(wc.x, wc.y, wc.z, wc.w, m7, xv[31], A, B, C, D);
  }

  // acc = 2*S_range + dot_range/4 per column -> 4*scales * acc here;
  // the 8*scales*S magic bias is cancelled in the by==0 correction below.
  const float4 sc = reinterpret_cast<const float4*>(scales)[tcol4];
  float4 contrib;
  contrib.x = 4.f * sc.x * A;
  contrib.y = 4.f * sc.y * B;
  contrib.z = 4.f * sc.z * C;
  contrib.w = 4.f * sc.w * D;

  if (blockIdx.y == 0) {
    // Fold in bias - (8*scales + zeros) * S.
    float s = 0.f;
    const float4* xall = reinterpret_cast<const float4*>(x);
    #pragma unroll
    for (int i = 0; i < (IN_FEAT / 4) / 64; ++i) {   // 32 float4 per lane
      float4 t = xall[i * 64 + threadIdx.x];
      s += (t.x + t.y) + (t.z + t.w);
    }
    #pragma unroll
    for (int off = 32; off > 0; off >>= 1) s += __shfl_xor(s, off, 64);
    const float S = s;                               // all lanes hold the total
    const float4 zr = reinterpret_cast<const float4*>(zeros)[tcol4];
    const float4 bi = reinterpret_cast<const float4*>(bias)[tcol4];
    contrib.x += bi.x - (8.f * sc.x + zr.x) * S;
    contrib.y += bi.y - (8.f * sc.y + zr.y) * S;
    contrib.z += bi.z - (8.f * sc.z + zr.z) * S;
    contrib.w += bi.w - (8.f * sc.w + zr.w) * S;
  }

  // z layers 0..1 -> dummy regions (measurement amplification); z==2 -> out.
  float* target = (blockIdx.z == NREP - 1)
                    ? out
                    : dummy + (size_t)blockIdx.z * O_FEAT;
  float* op = target + 4 * (size_t)tcol4;
  atomicAdd(op + 0, contrib.x);
  atomicAdd(op + 1, contrib.y);
  atomicAdd(op + 2, contrib.z);
  atomicAdd(op + 3, contrib.w);
}

extern "C" void kernel_launch(void* const* d_in, const int* in_sizes, int n_in,
                              void* d_out, int out_size, void* d_ws, size_t ws_size,
                              hipStream_t stream) {
  const float* x      = (const float*)d_in[0];
  const uint4* qw4    = (const uint4*)d_in[1];
  const float* scales = (const float*)d_in[2];
  const float* zeros  = (const float*)d_in[3];
  const float* bias   = (const float*)d_in[4];
  float*       out    = (float*)d_out;
  float*       dummy  = (float*)d_ws;   // 2 * O_FEAT floats = 224 KB scratch

  q3_onepass<<<dim3(NBX, SPLIT, NREP), dim3(64), 0, stream>>>(
      x, qw4, scales, zeros, bias, out, dummy);
}

// Round 19
// 139.097 us; speedup vs baseline: 1.2864x; 1.2864x over previous
//
#include <hip/hip_runtime.h>
#include <stdint.h>

// Quant3Linear GEMV: y = x @ (scales.T * unpack3(qweight) - zeros.T) + bias
//   x: (1, 8192) f32 | qweight: (768, 28672) i32 | scales,zeros: (28672,1) | bias: (28672,)
// Decomposition: y[o] = scales[o]*dot(x, q[:,o]) - zeros[o]*sum(x) + bias[o]
//
// R19: SGPR-x VIA EXPLICIT s_load (asm, uncanonicalizable). R18 profiled the
// real asm kernel: 27.8us/layer, VALUBusy 66.6% -> ~34% idle; the only
// loop-resident wait left is the lgkm path (64 ds_read_b128 of x per wave).
// x is WAVE-UNIFORM: load each group's 32 floats with two s_load_dwordx16
// into SGPR-16 vectors, issued ONE GROUP AHEAD (SMEM latency hides under
// ~800cy of compute), drained by s_waitcnt lgkmcnt(0) routed through a
// tied-operand asm (dataflow-ordered; lgkmcnt(0) mandatory -- SMEM returns
// out of order). fmac becomes v_fmac_f32 vA, sX, vT (VOP2 src0=SGPR legal,
// 1 SGPR read/inst). Deletes ALL LDS use, all ds_reads, ~32 VGPRs of xv.
// Compute otherwise R16: 3-VALU/elem asm dot (lshl; and_or SGPR-mask +
// inline-2.0 base -> 2+c/4; fmac), depth-2 qweight window, counted vmcnt.
// y = 4*sc*acc - (8*sc+zr)*S + bias; fence-free atomic epilogue (R9).
// History: depth-2 window -3.9us (R16); depth-4 neutral (R17); asm-vs-HIP
//   inst count neutral (R15); TLP dead (R1,R11); memory dead (R10);
//   fences toxic (R8); coop fails (R7).

constexpr int O_FEAT  = 28672;
constexpr int IN_FEAT = 8192;
constexpr int NGROUP  = IN_FEAT / 32;   // 256 groups (3 packed int32 rows each)
constexpr int SPLIT   = 32;             // split-K factor
constexpr int GPB     = NGROUP / SPLIT; // 8 groups per thread
constexpr int O4      = O_FEAT / 4;     // uint4 columns per packed row
constexpr int NBX     = O4 / 64;        // 112 column groups (256 cols each)
constexpr int PFD     = 2;              // qweight prefetch depth (R16 best)

typedef float sf16 __attribute__((ext_vector_type(16)));

// Issue 32 uniform x floats (128 B) from SGPR-pair base p into two SGPR-16
// vectors. No wait here -- drained later via swait (one group ahead).
__device__ __forceinline__ void sload_x(const float* p, sf16& lo, sf16& hi) {
  asm volatile("s_load_dwordx16 %0, %2, 0\n\t"
               "s_load_dwordx16 %1, %2, 64"
               : "=s"(lo), "=s"(hi)
               : "s"(p));
}

// Drain SMEM returns; tied operands make every later read of lo/hi
// data-depend on the wait (compiler cannot hoist consumers above it).
__device__ __forceinline__ void swait(sf16& lo, sf16& hi) {
  asm volatile("s_waitcnt lgkmcnt(0)" : "+s"(lo), "+s"(hi));
}

// One regular element (field at bit SH of per-column word) for 4 columns.
// xj is an SGPR (wave-uniform x value): v_fmac_f32 src0=SGPR is legal.
template <int SH>
__device__ __forceinline__ void q3e4(uint32_t va, uint32_t vb, uint32_t vc, uint32_t vd,
                                     uint32_t m7, float xj,
                                     float& A, float& B, float& C, float& D) {
  float t0, t1, t2, t3;
  if constexpr (SH < 20) {
    asm("v_lshlrev_b32 %0, %12, %8\n\t"
        "v_lshlrev_b32 %1, %12, %9\n\t"
        "v_lshlrev_b32 %2, %12, %10\n\t"
        "v_lshlrev_b32 %3, %12, %11\n\t"
        "v_and_or_b32 %0, %0, %13, 2.0\n\t"
        "v_and_or_b32 %1, %1, %13, 2.0\n\t"
        "v_and_or_b32 %2, %2, %13, 2.0\n\t"
        "v_and_or_b32 %3, %3, %13, 2.0\n\t"
        "v_fmac_f32 %4, %14, %0\n\t"
        "v_fmac_f32 %5, %14, %1\n\t"
        "v_fmac_f32 %6, %14, %2\n\t"
        "v_fmac_f32 %7, %14, %3"
        : "=&v"(t0), "=&v"(t1), "=&v"(t2), "=&v"(t3),
          "+v"(A), "+v"(B), "+v"(C), "+v"(D)
        : "v"(va), "v"(vb), "v"(vc), "v"(vd), "n"(20 - SH), "s"(m7), "s"(xj));
  } else if constexpr (SH == 20) {
    asm("v_and_or_b32 %0, %8, %12, 2.0\n\t"
        "v_and_or_b32 %1, %9, %12, 2.0\n\t"
        "v_and_or_b32 %2, %10, %12, 2.0\n\t"
        "v_and_or_b32 %3, %11, %12, 2.0\n\t"
        "v_fmac_f32 %4, %13, %0\n\t"
        "v_fmac_f32 %5, %13, %1\n\t"
        "v_fmac_f32 %6, %13, %2\n\t"
        "v_fmac_f32 %7, %13, %3"
        : "=&v"(t0), "=&v"(t1), "=&v"(t2), "=&v"(t3),
          "+v"(A), "+v"(B), "+v"(C), "+v"(D)
        : "v"(va), "v"(vb), "v"(vc), "v"(vd), "s"(m7), "s"(xj));
  } else {
    asm("v_lshrrev_b32 %0, %12, %8\n\t"
        "v_lshrrev_b32 %1, %12, %9\n\t"
        "v_lshrrev_b32 %2, %12, %10\n\t"
        "v_lshrrev_b32 %3, %12, %11\n\t"
        "v_and_or_b32 %0, %0, %13, 2.0\n\t"
        "v_and_or_b32 %1, %1, %13, 2.0\n\t"
        "v_and_or_b32 %2, %2, %13, 2.0\n\t"
        "v_and_or_b32 %3, %3, %13, 2.0\n\t"
        "v_fmac_f32 %4, %14, %0\n\t"
        "v_fmac_f32 %5, %14, %1\n\t"
        "v_fmac_f32 %6, %14, %2\n\t"
        "v_fmac_f32 %7, %14, %3"
        : "=&v"(t0), "=&v"(t1), "=&v"(t2), "=&v"(t3),
          "+v"(A), "+v"(B), "+v"(C), "+v"(D)
        : "v"(va), "v"(vb), "v"(vc), "v"(vd), "n"(SH - 20), "s"(m7), "s"(xj));
  }
}

// e10 = (w0>>30)|((w1&1)<<2): u = ((w0>>10)&0x300000)|((w1<<22)&0x400000)|2.0
__device__ __forceinline__ void q3e4_s10(uint4 wa, uint4 wb, uint32_t m3, uint32_t m4,
                                         float xj, float& A, float& B, float& C, float& D) {
  float t0, t1, t2, t3, u0, u1, u2, u3;
  asm("v_lshrrev_b32 %0, 10, %12\n\t"
      "v_lshrrev_b32 %1, 10, %13\n\t"
      "v_lshrrev_b32 %2, 10, %14\n\t"
      "v_lshrrev_b32 %3, 10, %15\n\t"
      "v_lshlrev_b32 %4, 22, %16\n\t"
      "v_lshlrev_b32 %5, 22, %17\n\t"
      "v_lshlrev_b32 %6, 22, %18\n\t"
      "v_lshlrev_b32 %7, 22, %19\n\t"
      "v_and_or_b32 %0, %0, %20, 2.0\n\t"
      "v_and_or_b32 %1, %1, %20, 2.0\n\t"
      "v_and_or_b32 %2, %2, %20, 2.0\n\t"
      "v_and_or_b32 %3, %3, %20, 2.0\n\t"
      "v_and_or_b32 %0, %4, %21, %0\n\t"
      "v_and_or_b32 %1, %5, %21, %1\n\t"
      "v_and_or_b32 %2, %6, %21, %2\n\t"
      "v_and_or_b32 %3, %7, %21, %3\n\t"
      "v_fmac_f32 %8, %22, %0\n\t"
      "v_fmac_f32 %9, %22, %1\n\t"
      "v_fmac_f32 %10, %22, %2\n\t"
      "v_fmac_f32 %11, %22, %3"
      : "=&v"(t0), "=&v"(t1), "=&v"(t2), "=&v"(t3),
        "=&v"(u0), "=&v"(u1), "=&v"(u2), "=&v"(u3),
        "+v"(A), "+v"(B), "+v"(C), "+v"(D)
      : "v"(wa.x), "v"(wa.y), "v"(wa.z), "v"(wa.w),
        "v"(wb.x), "v"(wb.y), "v"(wb.z), "v"(wb.w),
        "s"(m3), "s"(m4), "s"(xj));
}

// e21 = (w1>>31)|((w2&3)<<1): u = ((w1>>11)&0x100000)|((w2<<21)&0x600000)|2.0
__device__ __forceinline__ void q3e4_s21(uint4 wb, uint4 wc, uint32_t m1, uint32_t m6,
                                         float xj, float& A, float& B, float& C, float& D) {
  float t0, t1, t2, t3, u0, u1, u2, u3;
  asm("v_lshrrev_b32 %0, 11, %12\n\t"
      "v_lshrrev_b32 %1, 11, %13\n\t"
      "v_lshrrev_b32 %2, 11, %14\n\t"
      "v_lshrrev_b32 %3, 11, %15\n\t"
      "v_lshlrev_b32 %4, 21, %16\n\t"
      "v_lshlrev_b32 %5, 21, %17\n\t"
      "v_lshlrev_b32 %6, 21, %18\n\t"
      "v_lshlrev_b32 %7, 21, %19\n\t"
      "v_and_or_b32 %0, %0, %20, 2.0\n\t"
      "v_and_or_b32 %1, %1, %20, 2.0\n\t"
      "v_and_or_b32 %2, %2, %20, 2.0\n\t"
      "v_and_or_b32 %3, %3, %20, 2.0\n\t"
      "v_and_or_b32 %0, %4, %21, %0\n\t"
      "v_and_or_b32 %1, %5, %21, %1\n\t"
      "v_and_or_b32 %2, %6, %21, %2\n\t"
      "v_and_or_b32 %3, %7, %21, %3\n\t"
      "v_fmac_f32 %8, %22, %0\n\t"
      "v_fmac_f32 %9, %22, %1\n\t"
      "v_fmac_f32 %10, %22, %2\n\t"
      "v_fmac_f32 %11, %22, %3"
      : "=&v"(t0), "=&v"(t1), "=&v"(t2), "=&v"(t3),
        "=&v"(u0), "=&v"(u1), "=&v"(u2), "=&v"(u3),
        "+v"(A), "+v"(B), "+v"(C), "+v"(D)
      : "v"(wb.x), "v"(wb.y), "v"(wb.z), "v"(wb.w),
        "v"(wc.x), "v"(wc.y), "v"(wc.z), "v"(wc.w),
        "s"(m1), "s"(m6), "s"(xj));
}

__global__ __launch_bounds__(64) void q3_onepass(const float* __restrict__ x,
                                                 const uint4* __restrict__ qw4,
                                                 const float* __restrict__ scales,
                                                 const float* __restrict__ zeros,
                                                 const float* __restrict__ bias,
                                                 float* __restrict__ out) {
  const int tcol4 = blockIdx.x * 64 + threadIdx.x;   // index in units of 4 columns
  const int g0    = blockIdx.y * GPB;
  const uint4* qp = qw4 + (size_t)(3 * g0) * O4 + tcol4;
  const float* xb = x + g0 * 32;                     // uniform base (SGPR pair)

  const uint32_t m7 = 0x00700000u, m3 = 0x00300000u, m4 = 0x00400000u,
                 m1 = 0x00100000u, m6 = 0x00600000u;

  float A = 0.f, B = 0.f, C = 0.f, D = 0.f;   // 4 column accumulators

  // x ping-pong in SGPRs: prologue loads group 0 and waits once (~200cy,
  // paid once); thereafter group g+1's s_loads fly under group g's compute.
  sf16 xa0, xa1, xb0, xb1;
  sload_x(xb, xa0, xa1);
  swait(xa0, xa1);

  // Depth-2 qweight sliding window (R16 best): counted vmcnt, never 0.
  uint4 w[GPB][3];
  #pragma unroll
  for (int g = 0; g < PFD; ++g) {
    w[g][0] = qp[0]; w[g][1] = qp[O4]; w[g][2] = qp[2 * O4];
    qp += 3 * O4;
  }

  #pragma unroll
  for (int g = 0; g < GPB; ++g) {
    const bool odd = (g & 1);            // compile-time after unroll
    sf16& clo = odd ? xb0 : xa0;
    sf16& chi = odd ? xb1 : xa1;
    sf16& nlo = odd ? xa0 : xb0;
    sf16& nhi = odd ? xa1 : xb1;

    if (g + 1 < GPB) sload_x(xb + (g + 1) * 32, nlo, nhi);  // issue early

    if (g + PFD < GPB) {
      w[g + PFD][0] = qp[0]; w[g + PFD][1] = qp[O4]; w[g + PFD][2] = qp[2 * O4];
      qp += 3 * O4;
    }
    const uint4 wa = w[g][0], wb = w[g][1], wc = w[g][2];

    // word0: e0..e9 at sh=3j  (x from SGPRs: clo[j] / chi[j-16])
    q3e4<0>(wa.x, wa.y, wa.z, wa.w, m7, clo[0], A, B, C, D);
    q3e4<3>(wa.x, wa.y, wa.z, wa.w, m7, clo[1], A, B, C, D);
    q3e4<6>(wa.x, wa.y, wa.z, wa.w, m7, clo[2], A, B, C, D);
    q3e4<9>(wa.x, wa.y, wa.z, wa.w, m7, clo[3], A, B, C, D);
    q3e4<12>(wa.x, wa.y, wa.z, wa.w, m7, clo[4], A, B, C, D);
    q3e4<15>(wa.x, wa.y, wa.z, wa.w, m7, clo[5], A, B, C, D);
    q3e4<18>(wa.x, wa.y, wa.z, wa.w, m7, clo[6], A, B, C, D);
    q3e4<21>(wa.x, wa.y, wa.z, wa.w, m7, clo[7], A, B, C, D);
    q3e4<24>(wa.x, wa.y, wa.z, wa.w, m7, clo[8], A, B, C, D);
    q3e4<27>(wa.x, wa.y, wa.z, wa.w, m7, clo[9], A, B, C, D);
    // e10 split w0/w1
    q3e4_s10(wa, wb, m3, m4, clo[10], A, B, C, D);
    // word1: e11..e20 at sh=3j+1
    q3e4<1>(wb.x, wb.y, wb.z, wb.w, m7, clo[11], A, B, C, D);
    q3e4<4>(wb.x, wb.y, wb.z, wb.w, m7, clo[12], A, B, C, D);
    q3e4<7>(wb.x, wb.y, wb.z, wb.w, m7, clo[13], A, B, C, D);
    q3e4<10>(wb.x, wb.y, wb.z, wb.w, m7, clo[14], A, B, C, D);
    q3e4<13>(wb.x, wb.y, wb.z, wb.w, m7, clo[15], A, B, C, D);
    q3e4<16>(wb.x, wb.y, wb.z, wb.w, m7, chi[0], A, B, C, D);
    q3e4<19>(wb.x, wb.y, wb.z, wb.w, m7, chi[1], A, B, C, D);
    q3e4<22>(wb.x, wb.y, wb.z, wb.w, m7, chi[2], A, B, C, D);
    q3e4<25>(wb.x, wb.y, wb.z, wb.w, m7, chi[3], A, B, C, D);
    q3e4<28>(wb.x, wb.y, wb.z, wb.w, m7, chi[4], A, B, C, D);
    // e21 split w1/w2
    q3e4_s21(wb, wc, m1, m6, chi[5], A, B, C, D);
    // word2: e22..e31 at sh=3j+2
    q3e4<2>(wc.x, wc.y, wc.z, wc.w, m7, chi[6], A, B, C, D);
    q3e4<5>(wc.x, wc.y, wc.z, wc.w, m7, chi[7], A, B, C, D);
    q3e4<8>(wc.x, wc.y, wc.z, wc.w, m7, chi[8], A, B, C, D);
    q3e4<11>(wc.x, wc.y, wc.z, wc.w, m7, chi[9], A, B, C, D);
    q3e4<14>(wc.x, wc.y, wc.z, wc.w, m7, chi[10], A, B, C, D);
    q3e4<17>(wc.x, wc.y, wc.z, wc.w, m7, chi[11], A, B, C, D);
    q3e4<20>(wc.x, wc.y, wc.z, wc.w, m7, chi[12], A, B, C, D);
    q3e4<23>(wc.x, wc.y, wc.z, wc.w, m7, chi[13], A, B, C, D);
    q3e4<26>(wc.x, wc.y, wc.z, wc.w, m7, chi[14], A, B, C, D);
    q3e4<29>(wc.x, wc.y, wc.z, wc.w, m7, chi[15], A, B, C, D);

    if (g + 1 < GPB) swait(nlo, nhi);    // drain g+1's x before its use
  }

  // acc = 2*S_range + dot_range/4 per column -> 4*scales * acc here;
  // the 8*scales*S magic bias is cancelled in the by==0 correction below.
  const float4 sc = reinterpret_cast<const float4*>(scales)[tcol4];
  float4 contrib;
  contrib.x = 4.f * sc.x * A;
  contrib.y = 4.f * sc.y * B;
  contrib.z = 4.f * sc.z * C;
  contrib.w = 4.f * sc.w * D;

  if (blockIdx.y == 0) {
    // Fold in bias - (8*scales + zeros) * S.
    float s = 0.f;
    const float4* xall = reinterpret_cast<const float4*>(x);
    #pragma unroll
    for (int i = 0; i < (IN_FEAT / 4) / 64; ++i) {   // 32 float4 per lane
      float4 t = xall[i * 64 + threadIdx.x];
      s += (t.x + t.y) + (t.z + t.w);
    }
    #pragma unroll
    for (int off = 32; off > 0; off >>= 1) s += __shfl_xor(s, off, 64);
    const float S = s;                               // all lanes hold the total
    const float4 zr = reinterpret_cast<const float4*>(zeros)[tcol4];
    const float4 bi = reinterpret_cast<const float4*>(bias)[tcol4];
    contrib.x += bi.x - (8.f * sc.x + zr.x) * S;
    contrib.y += bi.y - (8.f * sc.y + zr.y) * S;
    contrib.z += bi.z - (8.f * sc.z + zr.z) * S;
    contrib.w += bi.w - (8.f * sc.w + zr.w) * S;
  }

  float* op = out + 4 * (size_t)tcol4;
  atomicAdd(op + 0, contrib.x);
  atomicAdd(op + 1, contrib.y);
  atomicAdd(op + 2, contrib.z);
  atomicAdd(op + 3, contrib.w);
}

extern "C" void kernel_launch(void* const* d_in, const int* in_sizes, int n_in,
                              void* d_out, int out_size, void* d_ws, size_t ws_size,
                              hipStream_t stream) {
  const float* x      = (const float*)d_in[0];
  const uint4* qw4    = (const uint4*)d_in[1];
  const float* scales = (const float*)d_in[2];
  const float* zeros  = (const float*)d_in[3];
  const float* bias   = (const float*)d_in[4];
  float*       out    = (float*)d_out;

  q3_onepass<<<dim3(NBX, SPLIT), dim3(64), 0, stream>>>(x, qw4, scales, zeros,
                                                        bias, out);
}